// Round 5
// baseline (294.536 us; speedup 1.0000x reference)
//
#include <hip/hip_runtime.h>

// WKV (RWKV v4), fully fused single kernel, register-resident chunks.
//
// Block = 1024 threads = 128 chunks x 8 channel-group threads; owns one
// (batch b, 32-channel tile). Grid = B * C/32 = 512 blocks.
//
//   Phase 0: load this thread's ENTIRE chunk (CHL=8 rows x k,v float4 =
//            16 float4 = 64 VGPRs) into registers in one burst. This is
//            the latency-hiding fix: round-4's compiler schedule (VGPR=52)
//            dribbled loads one row at a time; keeping the chunk live
//            through phase 3 forces all 16 loads in flight.
//   Phase 1: scan the chunk from identity -> local state (aa,bb,pp).
//   Phase 2: Hillis-Steele exclusive scan over 128 chunk states in LDS
//            (7 rounds). Operand at distance d spans d*CHL steps.
//   Phase 3: recompute outputs from the REGISTER-cached k,v (no L3
//            re-read at all) and emit y non-temporally.
//
// __launch_bounds__(1024,4): 4 waves/SIMD -> VGPR cap 128 (cache 64 +
// state/temps ~50). Tripwire for spills: WRITE_SIZE > 65 MB.
//
// All state in log2 domain (w,u,k pre-scaled by log2 e): every exponential
// is a bare v_exp_f32.

#define T_FIX  1024
#define NCH    128
#define CHL    (T_FIX / NCH)      // 8
#define CTILE  32                 // channels per block (128B rows)
#define CGT    (CTILE / 4)        // 8 channel-group threads
#define NTHR   (NCH * CGT)        // 1024
#define L2E    1.4426950408889634f

typedef float vfloat4 __attribute__((ext_vector_type(4)));

#define F4TOA(a, f) { a[0] = (f).x; a[1] = (f).y; a[2] = (f).z; a[3] = (f).w; }

__device__ __forceinline__ void wkv_step2(float& aa, float& bb, float& pp,
                                          float w2, float k2, float vt)
{
    float ww2 = pp + w2;
    float q2  = fmaxf(ww2, k2);
    float e1  = exp2f(ww2 - q2);
    float e2  = exp2f(k2 - q2);
    aa = fmaf(e1, aa, e2 * vt);
    bb = fmaf(e1, bb, e2);
    pp = q2;
}

__global__ __launch_bounds__(NTHR, 4)
void wkv_fused(const float* __restrict__ td,
               const float* __restrict__ tf,
               const float* __restrict__ k,
               const float* __restrict__ v,
               float* __restrict__ y,
               int B, int C)
{
    __shared__ float4 a_s[NTHR];
    __shared__ float4 b_s[NTHR];
    __shared__ float4 p_s[NTHR];

    const int tid = threadIdx.x;
    const int cg  = tid & (CGT - 1);     // channel group within tile
    const int j   = tid >> 3;            // chunk index 0..127

    const int tiles = C / CTILE;
    const int b  = blockIdx.x / tiles;
    const int c  = (blockIdx.x % tiles) * CTILE + (cg << 2);

    const size_t base = ((size_t)b * T_FIX + (size_t)j * CHL) * C + c;
    const float* kp = k + base;
    const float* vp = v + base;
    float*       yp = y + base;

    // ---------------- phase 0: register-cache the whole chunk ----------------
    float4 kc[CHL], vc[CHL];
    #pragma unroll
    for (int i = 0; i < CHL; ++i) {
        kc[i] = *(const float4*)(kp + (size_t)i * C);
        vc[i] = *(const float4*)(vp + (size_t)i * C);
    }

    float4 tdv = *(const float4*)(td + c);
    float4 tfv = *(const float4*)(tf + c);
    float w2[4] = { -__expf(tdv.x) * L2E, -__expf(tdv.y) * L2E,
                    -__expf(tdv.z) * L2E, -__expf(tdv.w) * L2E };
    float u2[4] = { tfv.x * L2E, tfv.y * L2E, tfv.z * L2E, tfv.w * L2E };

    // ---------------- phase 1: local chunk state ----------------
    float aa[4] = {0.f, 0.f, 0.f, 0.f};
    float bb[4] = {0.f, 0.f, 0.f, 0.f};
    float pp[4] = {-1e38f, -1e38f, -1e38f, -1e38f};

    #pragma unroll
    for (int i = 0; i < CHL; ++i) {
        float ka[4], va[4];
        F4TOA(ka, kc[i]); F4TOA(va, vc[i]);
        #pragma unroll
        for (int cc = 0; cc < 4; ++cc)
            wkv_step2(aa[cc], bb[cc], pp[cc], w2[cc], ka[cc] * L2E, va[cc]);
    }

    a_s[tid] = make_float4(aa[0], aa[1], aa[2], aa[3]);
    b_s[tid] = make_float4(bb[0], bb[1], bb[2], bb[3]);
    p_s[tid] = make_float4(pp[0], pp[1], pp[2], pp[3]);
    __syncthreads();

    // ---------------- phase 2: Hillis-Steele scan over chunks ----------------
    #pragma unroll
    for (int d = 1; d < NCH; d <<= 1) {
        float pa[4], pb[4], pm[4];
        const bool act = (j >= d);
        if (act) {
            float4 xa = a_s[tid - CGT * d];
            float4 xb = b_s[tid - CGT * d];
            float4 xp = p_s[tid - CGT * d];
            F4TOA(pa, xa); F4TOA(pb, xb); F4TOA(pm, xp);
        }
        __syncthreads();
        if (act) {
            const float Ld = (float)(d * CHL);   // steps the own value spans
            #pragma unroll
            for (int cc = 0; cc < 4; ++cc) {
                float ppd = fmaf(Ld, w2[cc], pm[cc]);   // decay predecessor
                float pn  = fmaxf(ppd, pp[cc]);
                float ea  = exp2f(ppd - pn);
                float eb  = exp2f(pp[cc] - pn);
                aa[cc] = fmaf(ea, pa[cc], eb * aa[cc]);
                bb[cc] = fmaf(ea, pb[cc], eb * bb[cc]);
                pp[cc] = pn;
            }
            a_s[tid] = make_float4(aa[0], aa[1], aa[2], aa[3]);
            b_s[tid] = make_float4(bb[0], bb[1], bb[2], bb[3]);
            p_s[tid] = make_float4(pp[0], pp[1], pp[2], pp[3]);
        }
        __syncthreads();
    }

    // exclusive prefix for this chunk = inclusive value of chunk j-1
    if (j > 0) {
        float4 xa = a_s[tid - CGT];
        float4 xb = b_s[tid - CGT];
        float4 xp = p_s[tid - CGT];
        F4TOA(aa, xa); F4TOA(bb, xb); F4TOA(pp, xp);
    } else {
        #pragma unroll
        for (int cc = 0; cc < 4; ++cc) { aa[cc] = 0.f; bb[cc] = 0.f; pp[cc] = -1e38f; }
    }

    // ---------------- phase 3: emit y from register-cached chunk ----------------
    #pragma unroll
    for (int i = 0; i < CHL; ++i) {
        float ka[4], va[4], ya[4];
        F4TOA(ka, kc[i]); F4TOA(va, vc[i]);
        #pragma unroll
        for (int cc = 0; cc < 4; ++cc) {
            float k2 = ka[cc] * L2E;
            float ww = u2[cc] + k2;
            float q  = fmaxf(pp[cc], ww);
            float e1 = exp2f(pp[cc] - q);
            float e2 = exp2f(ww - q);
            ya[cc] = __fdividef(fmaf(e1, aa[cc], e2 * va[cc]),
                                fmaf(e1, bb[cc], e2));
            wkv_step2(aa[cc], bb[cc], pp[cc], w2[cc], k2, va[cc]);
        }
        vfloat4 yo = { ya[0], ya[1], ya[2], ya[3] };
        __builtin_nontemporal_store(yo, (vfloat4*)(yp + (size_t)i * C));
    }
}

extern "C" void kernel_launch(void* const* d_in, const int* in_sizes, int n_in,
                              void* d_out, int out_size, void* d_ws, size_t ws_size,
                              hipStream_t stream)
{
    const float* td = (const float*)d_in[3];
    const float* tf = (const float*)d_in[4];
    const float* k  = (const float*)d_in[5];
    const float* v  = (const float*)d_in[6];
    float*       y  = (float*)d_out;

    const int C   = in_sizes[3];
    const int BTC = in_sizes[5];
    const int B   = BTC / (T_FIX * C);

    const int grid = B * (C / CTILE);
    wkv_fused<<<grid, NTHR, 0, stream>>>(td, tf, k, v, y, B, C);
}

// Round 6
// 277.618 us; speedup vs baseline: 1.0609x; 1.0609x over previous
//
#include <hip/hip_runtime.h>

// WKV (RWKV v4), fully fused single kernel, max-occupancy streaming.
//
// Round-4 (94us kernel) analysis: traffic is at the compulsory minimum
// (201MB -> 32us floor) but only 16 waves/CU theoretical. Round-5's
// register-cache attempt spilled (64-VGPR budget can't hold a 64-reg
// cache). This round doubles TLP instead:
//
// Block = 1024 threads = 128 chunks x 8 channel-group threads; owns one
// (batch b, 32-channel tile). Grid = B * C/32 = 512 blocks = 2 blocks/CU
// = 32 waves/CU (the hardware max).
//
//   Phase 1: stream chunk (CHL=8 rows, BATCH=4) -> local state.
//   Phase 2: Hillis-Steele exclusive scan over 128 chunk states in LDS
//            (7 rounds). Operand at distance d spans d*CHL steps.
//   Phase 3: re-stream chunk (L3-resident) and emit y non-temporally.
//
// __launch_bounds__(1024,8): 8 waves/EU -> VGPR cap 64; the streaming
// body chose 52 VGPRs in round 4, BATCH=4 staging is 32 regs. Spill
// tripwire: WRITE_SIZE > 66 MB.
//
// All state in log2 domain (w,u,k pre-scaled by log2 e): every exponential
// is a bare v_exp_f32.

#define T_FIX  1024
#define NCH    128
#define CHL    (T_FIX / NCH)      // 8
#define BATCH  4
#define CTILE  32                 // channels per block (128B rows)
#define CGT    (CTILE / 4)        // 8 channel-group threads
#define NTHR   (NCH * CGT)        // 1024
#define L2E    1.4426950408889634f

typedef float vfloat4 __attribute__((ext_vector_type(4)));

#define F4TOA(a, f) { a[0] = (f).x; a[1] = (f).y; a[2] = (f).z; a[3] = (f).w; }

__device__ __forceinline__ void wkv_step2(float& aa, float& bb, float& pp,
                                          float w2, float k2, float vt)
{
    float ww2 = pp + w2;
    float q2  = fmaxf(ww2, k2);
    float e1  = exp2f(ww2 - q2);
    float e2  = exp2f(k2 - q2);
    aa = fmaf(e1, aa, e2 * vt);
    bb = fmaf(e1, bb, e2);
    pp = q2;
}

__global__ __launch_bounds__(NTHR, 8)
void wkv_fused(const float* __restrict__ td,
               const float* __restrict__ tf,
               const float* __restrict__ k,
               const float* __restrict__ v,
               float* __restrict__ y,
               int B, int C)
{
    __shared__ float4 a_s[NTHR];
    __shared__ float4 b_s[NTHR];
    __shared__ float4 p_s[NTHR];

    const int tid = threadIdx.x;
    const int cg  = tid & (CGT - 1);     // channel group within tile
    const int j   = tid >> 3;            // chunk index 0..127

    const int tiles = C / CTILE;
    const int b  = blockIdx.x / tiles;
    const int c  = (blockIdx.x % tiles) * CTILE + (cg << 2);

    float4 tdv = *(const float4*)(td + c);
    float4 tfv = *(const float4*)(tf + c);
    float w2[4] = { -__expf(tdv.x) * L2E, -__expf(tdv.y) * L2E,
                    -__expf(tdv.z) * L2E, -__expf(tdv.w) * L2E };
    float u2[4] = { tfv.x * L2E, tfv.y * L2E, tfv.z * L2E, tfv.w * L2E };

    const size_t base = ((size_t)b * T_FIX + (size_t)j * CHL) * C + c;
    const float* kp = k + base;
    const float* vp = v + base;
    float*       yp = y + base;

    // ---------------- phase 1: local chunk state (streamed) ----------------
    float aa[4] = {0.f, 0.f, 0.f, 0.f};
    float bb[4] = {0.f, 0.f, 0.f, 0.f};
    float pp[4] = {-1e38f, -1e38f, -1e38f, -1e38f};

    for (int tb = 0; tb < CHL; tb += BATCH) {
        float4 kb[BATCH], vb[BATCH];
        #pragma unroll
        for (int i = 0; i < BATCH; ++i) {
            kb[i] = *(const float4*)(kp + (size_t)(tb + i) * C);
            vb[i] = *(const float4*)(vp + (size_t)(tb + i) * C);
        }
        #pragma unroll
        for (int i = 0; i < BATCH; ++i) {
            float ka[4], va[4];
            F4TOA(ka, kb[i]); F4TOA(va, vb[i]);
            #pragma unroll
            for (int cc = 0; cc < 4; ++cc)
                wkv_step2(aa[cc], bb[cc], pp[cc], w2[cc], ka[cc] * L2E, va[cc]);
        }
    }

    a_s[tid] = make_float4(aa[0], aa[1], aa[2], aa[3]);
    b_s[tid] = make_float4(bb[0], bb[1], bb[2], bb[3]);
    p_s[tid] = make_float4(pp[0], pp[1], pp[2], pp[3]);
    __syncthreads();

    // ---------------- phase 2: Hillis-Steele scan over chunks ----------------
    #pragma unroll
    for (int d = 1; d < NCH; d <<= 1) {
        float pa[4], pb[4], pm[4];
        const bool act = (j >= d);
        if (act) {
            float4 xa = a_s[tid - CGT * d];
            float4 xb = b_s[tid - CGT * d];
            float4 xp = p_s[tid - CGT * d];
            F4TOA(pa, xa); F4TOA(pb, xb); F4TOA(pm, xp);
        }
        __syncthreads();
        if (act) {
            const float Ld = (float)(d * CHL);   // steps the own value spans
            #pragma unroll
            for (int cc = 0; cc < 4; ++cc) {
                float ppd = fmaf(Ld, w2[cc], pm[cc]);   // decay predecessor
                float pn  = fmaxf(ppd, pp[cc]);
                float ea  = exp2f(ppd - pn);
                float eb  = exp2f(pp[cc] - pn);
                aa[cc] = fmaf(ea, pa[cc], eb * aa[cc]);
                bb[cc] = fmaf(ea, pb[cc], eb * bb[cc]);
                pp[cc] = pn;
            }
            a_s[tid] = make_float4(aa[0], aa[1], aa[2], aa[3]);
            b_s[tid] = make_float4(bb[0], bb[1], bb[2], bb[3]);
            p_s[tid] = make_float4(pp[0], pp[1], pp[2], pp[3]);
        }
        __syncthreads();
    }

    // exclusive prefix for this chunk = inclusive value of chunk j-1
    if (j > 0) {
        float4 xa = a_s[tid - CGT];
        float4 xb = b_s[tid - CGT];
        float4 xp = p_s[tid - CGT];
        F4TOA(aa, xa); F4TOA(bb, xb); F4TOA(pp, xp);
    } else {
        #pragma unroll
        for (int cc = 0; cc < 4; ++cc) { aa[cc] = 0.f; bb[cc] = 0.f; pp[cc] = -1e38f; }
    }

    // ---------------- phase 3: re-stream chunk, emit y ----------------
    for (int tb = 0; tb < CHL; tb += BATCH) {
        float4 kb[BATCH], vb[BATCH];
        #pragma unroll
        for (int i = 0; i < BATCH; ++i) {
            kb[i] = *(const float4*)(kp + (size_t)(tb + i) * C);
            vb[i] = *(const float4*)(vp + (size_t)(tb + i) * C);
        }
        #pragma unroll
        for (int i = 0; i < BATCH; ++i) {
            float ka[4], va[4], ya[4];
            F4TOA(ka, kb[i]); F4TOA(va, vb[i]);
            #pragma unroll
            for (int cc = 0; cc < 4; ++cc) {
                float k2 = ka[cc] * L2E;
                float ww = u2[cc] + k2;
                float q  = fmaxf(pp[cc], ww);
                float e1 = exp2f(pp[cc] - q);
                float e2 = exp2f(ww - q);
                ya[cc] = __fdividef(fmaf(e1, aa[cc], e2 * va[cc]),
                                    fmaf(e1, bb[cc], e2));
                wkv_step2(aa[cc], bb[cc], pp[cc], w2[cc], k2, va[cc]);
            }
            vfloat4 yo = { ya[0], ya[1], ya[2], ya[3] };
            __builtin_nontemporal_store(yo, (vfloat4*)(yp + (size_t)(tb + i) * C));
        }
    }
}

extern "C" void kernel_launch(void* const* d_in, const int* in_sizes, int n_in,
                              void* d_out, int out_size, void* d_ws, size_t ws_size,
                              hipStream_t stream)
{
    const float* td = (const float*)d_in[3];
    const float* tf = (const float*)d_in[4];
    const float* k  = (const float*)d_in[5];
    const float* v  = (const float*)d_in[6];
    float*       y  = (float*)d_out;

    const int C   = in_sizes[3];
    const int BTC = in_sizes[5];
    const int B   = BTC / (T_FIX * C);

    const int grid = B * (C / CTILE);
    wkv_fused<<<grid, NTHR, 0, stream>>>(td, tf, k, v, y, B, C);
}

// Round 7
// 219.411 us; speedup vs baseline: 1.3424x; 1.2653x over previous
//
#include <hip/hip_runtime.h>

// WKV (RWKV v4), fully fused single kernel, max-occupancy streaming.
//
// Calibration across rounds (measured VGPR caps): __launch_bounds__ 2nd
// arg N -> cap = 256/N on this compiler, regardless of block size.
//   R4: (512,2) cap128, chose 52, no spill, 16 waves/CU -> 94us
//   R6: (1024,8) cap32, SPILLED (231MB writes), 32 waves/CU -> 160us
// This round: (1024,4) cap64 -> round-4's 52-reg streaming body fits
// withOUT spill at round-6's 32 waves/CU occupancy.
//
// Block = 1024 threads = 128 chunks x 8 channel-group threads; owns one
// (batch b, 32-channel tile). Grid = B * C/32 = 512 blocks = 2 blocks/CU
// (LDS 48KB x2 = 96KB < 160KB) = 32 waves/CU.
//
//   Phase 1: stream chunk (CHL=8 rows, BATCH=4) -> local state.
//   Phase 2: Hillis-Steele exclusive scan over 128 chunk states in LDS
//            (7 rounds). Operand at distance d spans d*CHL steps.
//   Phase 3: re-stream chunk (L3-resident) and emit y non-temporally.
//
// Spill tripwire: WRITE_SIZE > 66 MB or FETCH_SIZE > 140 MB.
//
// All state in log2 domain (w,u,k pre-scaled by log2 e): every exponential
// is a bare v_exp_f32.

#define T_FIX  1024
#define NCH    128
#define CHL    (T_FIX / NCH)      // 8
#define BATCH  4
#define CTILE  32                 // channels per block (128B rows)
#define CGT    (CTILE / 4)        // 8 channel-group threads
#define NTHR   (NCH * CGT)        // 1024
#define L2E    1.4426950408889634f

typedef float vfloat4 __attribute__((ext_vector_type(4)));

#define F4TOA(a, f) { a[0] = (f).x; a[1] = (f).y; a[2] = (f).z; a[3] = (f).w; }

__device__ __forceinline__ void wkv_step2(float& aa, float& bb, float& pp,
                                          float w2, float k2, float vt)
{
    float ww2 = pp + w2;
    float q2  = fmaxf(ww2, k2);
    float e1  = exp2f(ww2 - q2);
    float e2  = exp2f(k2 - q2);
    aa = fmaf(e1, aa, e2 * vt);
    bb = fmaf(e1, bb, e2);
    pp = q2;
}

__global__ __launch_bounds__(NTHR, 4)
void wkv_fused(const float* __restrict__ td,
               const float* __restrict__ tf,
               const float* __restrict__ k,
               const float* __restrict__ v,
               float* __restrict__ y,
               int B, int C)
{
    __shared__ float4 a_s[NTHR];
    __shared__ float4 b_s[NTHR];
    __shared__ float4 p_s[NTHR];

    const int tid = threadIdx.x;
    const int cg  = tid & (CGT - 1);     // channel group within tile
    const int j   = tid >> 3;            // chunk index 0..127

    const int tiles = C / CTILE;
    const int b  = blockIdx.x / tiles;
    const int c  = (blockIdx.x % tiles) * CTILE + (cg << 2);

    float4 tdv = *(const float4*)(td + c);
    float4 tfv = *(const float4*)(tf + c);
    float w2[4] = { -__expf(tdv.x) * L2E, -__expf(tdv.y) * L2E,
                    -__expf(tdv.z) * L2E, -__expf(tdv.w) * L2E };
    float u2[4] = { tfv.x * L2E, tfv.y * L2E, tfv.z * L2E, tfv.w * L2E };

    const size_t base = ((size_t)b * T_FIX + (size_t)j * CHL) * C + c;
    const float* kp = k + base;
    const float* vp = v + base;
    float*       yp = y + base;

    // ---------------- phase 1: local chunk state (streamed) ----------------
    float aa[4] = {0.f, 0.f, 0.f, 0.f};
    float bb[4] = {0.f, 0.f, 0.f, 0.f};
    float pp[4] = {-1e38f, -1e38f, -1e38f, -1e38f};

    for (int tb = 0; tb < CHL; tb += BATCH) {
        float4 kb[BATCH], vb[BATCH];
        #pragma unroll
        for (int i = 0; i < BATCH; ++i) {
            kb[i] = *(const float4*)(kp + (size_t)(tb + i) * C);
            vb[i] = *(const float4*)(vp + (size_t)(tb + i) * C);
        }
        #pragma unroll
        for (int i = 0; i < BATCH; ++i) {
            float ka[4], va[4];
            F4TOA(ka, kb[i]); F4TOA(va, vb[i]);
            #pragma unroll
            for (int cc = 0; cc < 4; ++cc)
                wkv_step2(aa[cc], bb[cc], pp[cc], w2[cc], ka[cc] * L2E, va[cc]);
        }
    }

    a_s[tid] = make_float4(aa[0], aa[1], aa[2], aa[3]);
    b_s[tid] = make_float4(bb[0], bb[1], bb[2], bb[3]);
    p_s[tid] = make_float4(pp[0], pp[1], pp[2], pp[3]);
    __syncthreads();

    // ---------------- phase 2: Hillis-Steele scan over chunks ----------------
    #pragma unroll
    for (int d = 1; d < NCH; d <<= 1) {
        float pa[4], pb[4], pm[4];
        const bool act = (j >= d);
        if (act) {
            float4 xa = a_s[tid - CGT * d];
            float4 xb = b_s[tid - CGT * d];
            float4 xp = p_s[tid - CGT * d];
            F4TOA(pa, xa); F4TOA(pb, xb); F4TOA(pm, xp);
        }
        __syncthreads();
        if (act) {
            const float Ld = (float)(d * CHL);   // steps the own value spans
            #pragma unroll
            for (int cc = 0; cc < 4; ++cc) {
                float ppd = fmaf(Ld, w2[cc], pm[cc]);   // decay predecessor
                float pn  = fmaxf(ppd, pp[cc]);
                float ea  = exp2f(ppd - pn);
                float eb  = exp2f(pp[cc] - pn);
                aa[cc] = fmaf(ea, pa[cc], eb * aa[cc]);
                bb[cc] = fmaf(ea, pb[cc], eb * bb[cc]);
                pp[cc] = pn;
            }
            a_s[tid] = make_float4(aa[0], aa[1], aa[2], aa[3]);
            b_s[tid] = make_float4(bb[0], bb[1], bb[2], bb[3]);
            p_s[tid] = make_float4(pp[0], pp[1], pp[2], pp[3]);
        }
        __syncthreads();
    }

    // exclusive prefix for this chunk = inclusive value of chunk j-1
    if (j > 0) {
        float4 xa = a_s[tid - CGT];
        float4 xb = b_s[tid - CGT];
        float4 xp = p_s[tid - CGT];
        F4TOA(aa, xa); F4TOA(bb, xb); F4TOA(pp, xp);
    } else {
        #pragma unroll
        for (int cc = 0; cc < 4; ++cc) { aa[cc] = 0.f; bb[cc] = 0.f; pp[cc] = -1e38f; }
    }

    // ---------------- phase 3: re-stream chunk, emit y ----------------
    for (int tb = 0; tb < CHL; tb += BATCH) {
        float4 kb[BATCH], vb[BATCH];
        #pragma unroll
        for (int i = 0; i < BATCH; ++i) {
            kb[i] = *(const float4*)(kp + (size_t)(tb + i) * C);
            vb[i] = *(const float4*)(vp + (size_t)(tb + i) * C);
        }
        #pragma unroll
        for (int i = 0; i < BATCH; ++i) {
            float ka[4], va[4], ya[4];
            F4TOA(ka, kb[i]); F4TOA(va, vb[i]);
            #pragma unroll
            for (int cc = 0; cc < 4; ++cc) {
                float k2 = ka[cc] * L2E;
                float ww = u2[cc] + k2;
                float q  = fmaxf(pp[cc], ww);
                float e1 = exp2f(pp[cc] - q);
                float e2 = exp2f(ww - q);
                ya[cc] = __fdividef(fmaf(e1, aa[cc], e2 * va[cc]),
                                    fmaf(e1, bb[cc], e2));
                wkv_step2(aa[cc], bb[cc], pp[cc], w2[cc], k2, va[cc]);
            }
            vfloat4 yo = { ya[0], ya[1], ya[2], ya[3] };
            __builtin_nontemporal_store(yo, (vfloat4*)(yp + (size_t)(tb + i) * C));
        }
    }
}

extern "C" void kernel_launch(void* const* d_in, const int* in_sizes, int n_in,
                              void* d_out, int out_size, void* d_ws, size_t ws_size,
                              hipStream_t stream)
{
    const float* td = (const float*)d_in[3];
    const float* tf = (const float*)d_in[4];
    const float* k  = (const float*)d_in[5];
    const float* v  = (const float*)d_in[6];
    float*       y  = (float*)d_out;

    const int C   = in_sizes[3];
    const int BTC = in_sizes[5];
    const int B   = BTC / (T_FIX * C);

    const int grid = B * (C / CTILE);
    wkv_fused<<<grid, NTHR, 0, stream>>>(td, tf, k, v, y, B, C);
}

// Round 8
// 217.972 us; speedup vs baseline: 1.3513x; 1.0066x over previous
//
#include <hip/hip_runtime.h>

// WKV (RWKV v4), fully fused single kernel, max-occupancy streaming.
//
// Occupancy calibration (measured): VGPR=32 -> occ 79.5% (R6, spilled);
// VGPR=64 -> occ 35% (R7, no spill, 94.7us == R4's half-TLP time).
// The VGPR=64 boundary HALVES waves/SIMD (guide m69: steps at 64/128/256).
// The compiler does not pad to the cap (R4 chose 52 under cap 128) — it
// chose 64 in R7 because BATCH=4 staging (32 regs) forced it. This round:
// BATCH=2 (16 staging regs) under the same (1024,4) cap -> expect ~48-54
// VGPR -> 8 waves/SIMD, no spill. The "32 waves/CU + no spill" config
// has never actually run; this is that experiment.
//
// Block = 1024 threads = 128 chunks x 8 channel-group threads; owns one
// (batch b, 32-channel tile). Grid = B * C/32 = 512 blocks = 2 blocks/CU
// (LDS 48KB x2 = 96KB < 160KB) = 32 waves/CU if VGPR < 64.
//
//   Phase 1: stream chunk (CHL=8 rows, BATCH=2) -> local state.
//   Phase 2: Hillis-Steele exclusive scan over 128 chunk states in LDS
//            (7 rounds). Operand at distance d spans d*CHL steps.
//   Phase 3: re-stream chunk (L3-resident) and emit y non-temporally.
//
// Tripwires: VGPR >= 64 (occupancy bucket), WRITE_SIZE > 66 MB (spill).
//
// All state in log2 domain (w,u,k pre-scaled by log2 e): every exponential
// is a bare v_exp_f32.

#define T_FIX  1024
#define NCH    128
#define CHL    (T_FIX / NCH)      // 8
#define BATCH  2
#define CTILE  32                 // channels per block (128B rows)
#define CGT    (CTILE / 4)        // 8 channel-group threads
#define NTHR   (NCH * CGT)        // 1024
#define L2E    1.4426950408889634f

typedef float vfloat4 __attribute__((ext_vector_type(4)));

#define F4TOA(a, f) { a[0] = (f).x; a[1] = (f).y; a[2] = (f).z; a[3] = (f).w; }

__device__ __forceinline__ void wkv_step2(float& aa, float& bb, float& pp,
                                          float w2, float k2, float vt)
{
    float ww2 = pp + w2;
    float q2  = fmaxf(ww2, k2);
    float e1  = exp2f(ww2 - q2);
    float e2  = exp2f(k2 - q2);
    aa = fmaf(e1, aa, e2 * vt);
    bb = fmaf(e1, bb, e2);
    pp = q2;
}

__global__ __launch_bounds__(NTHR, 4)
void wkv_fused(const float* __restrict__ td,
               const float* __restrict__ tf,
               const float* __restrict__ k,
               const float* __restrict__ v,
               float* __restrict__ y,
               int B, int C)
{
    __shared__ float4 a_s[NTHR];
    __shared__ float4 b_s[NTHR];
    __shared__ float4 p_s[NTHR];

    const int tid = threadIdx.x;
    const int cg  = tid & (CGT - 1);     // channel group within tile
    const int j   = tid >> 3;            // chunk index 0..127

    const int tiles = C / CTILE;
    const int b  = blockIdx.x / tiles;
    const int c  = (blockIdx.x % tiles) * CTILE + (cg << 2);

    float4 tdv = *(const float4*)(td + c);
    float4 tfv = *(const float4*)(tf + c);
    float w2[4] = { -__expf(tdv.x) * L2E, -__expf(tdv.y) * L2E,
                    -__expf(tdv.z) * L2E, -__expf(tdv.w) * L2E };
    float u2[4] = { tfv.x * L2E, tfv.y * L2E, tfv.z * L2E, tfv.w * L2E };

    const size_t base = ((size_t)b * T_FIX + (size_t)j * CHL) * C + c;
    const float* kp = k + base;
    const float* vp = v + base;
    float*       yp = y + base;

    // ---------------- phase 1: local chunk state (streamed) ----------------
    float aa[4] = {0.f, 0.f, 0.f, 0.f};
    float bb[4] = {0.f, 0.f, 0.f, 0.f};
    float pp[4] = {-1e38f, -1e38f, -1e38f, -1e38f};

    for (int tb = 0; tb < CHL; tb += BATCH) {
        float4 kb[BATCH], vb[BATCH];
        #pragma unroll
        for (int i = 0; i < BATCH; ++i) {
            kb[i] = *(const float4*)(kp + (size_t)(tb + i) * C);
            vb[i] = *(const float4*)(vp + (size_t)(tb + i) * C);
        }
        #pragma unroll
        for (int i = 0; i < BATCH; ++i) {
            float ka[4], va[4];
            F4TOA(ka, kb[i]); F4TOA(va, vb[i]);
            #pragma unroll
            for (int cc = 0; cc < 4; ++cc)
                wkv_step2(aa[cc], bb[cc], pp[cc], w2[cc], ka[cc] * L2E, va[cc]);
        }
    }

    a_s[tid] = make_float4(aa[0], aa[1], aa[2], aa[3]);
    b_s[tid] = make_float4(bb[0], bb[1], bb[2], bb[3]);
    p_s[tid] = make_float4(pp[0], pp[1], pp[2], pp[3]);
    __syncthreads();

    // ---------------- phase 2: Hillis-Steele scan over chunks ----------------
    #pragma unroll
    for (int d = 1; d < NCH; d <<= 1) {
        float pa[4], pb[4], pm[4];
        const bool act = (j >= d);
        if (act) {
            float4 xa = a_s[tid - CGT * d];
            float4 xb = b_s[tid - CGT * d];
            float4 xp = p_s[tid - CGT * d];
            F4TOA(pa, xa); F4TOA(pb, xb); F4TOA(pm, xp);
        }
        __syncthreads();
        if (act) {
            const float Ld = (float)(d * CHL);   // steps the own value spans
            #pragma unroll
            for (int cc = 0; cc < 4; ++cc) {
                float ppd = fmaf(Ld, w2[cc], pm[cc]);   // decay predecessor
                float pn  = fmaxf(ppd, pp[cc]);
                float ea  = exp2f(ppd - pn);
                float eb  = exp2f(pp[cc] - pn);
                aa[cc] = fmaf(ea, pa[cc], eb * aa[cc]);
                bb[cc] = fmaf(ea, pb[cc], eb * bb[cc]);
                pp[cc] = pn;
            }
            a_s[tid] = make_float4(aa[0], aa[1], aa[2], aa[3]);
            b_s[tid] = make_float4(bb[0], bb[1], bb[2], bb[3]);
            p_s[tid] = make_float4(pp[0], pp[1], pp[2], pp[3]);
        }
        __syncthreads();
    }

    // exclusive prefix for this chunk = inclusive value of chunk j-1
    if (j > 0) {
        float4 xa = a_s[tid - CGT];
        float4 xb = b_s[tid - CGT];
        float4 xp = p_s[tid - CGT];
        F4TOA(aa, xa); F4TOA(bb, xb); F4TOA(pp, xp);
    } else {
        #pragma unroll
        for (int cc = 0; cc < 4; ++cc) { aa[cc] = 0.f; bb[cc] = 0.f; pp[cc] = -1e38f; }
    }

    // ---------------- phase 3: re-stream chunk, emit y ----------------
    for (int tb = 0; tb < CHL; tb += BATCH) {
        float4 kb[BATCH], vb[BATCH];
        #pragma unroll
        for (int i = 0; i < BATCH; ++i) {
            kb[i] = *(const float4*)(kp + (size_t)(tb + i) * C);
            vb[i] = *(const float4*)(vp + (size_t)(tb + i) * C);
        }
        #pragma unroll
        for (int i = 0; i < BATCH; ++i) {
            float ka[4], va[4], ya[4];
            F4TOA(ka, kb[i]); F4TOA(va, vb[i]);
            #pragma unroll
            for (int cc = 0; cc < 4; ++cc) {
                float k2 = ka[cc] * L2E;
                float ww = u2[cc] + k2;
                float q  = fmaxf(pp[cc], ww);
                float e1 = exp2f(pp[cc] - q);
                float e2 = exp2f(ww - q);
                ya[cc] = __fdividef(fmaf(e1, aa[cc], e2 * va[cc]),
                                    fmaf(e1, bb[cc], e2));
                wkv_step2(aa[cc], bb[cc], pp[cc], w2[cc], k2, va[cc]);
            }
            vfloat4 yo = { ya[0], ya[1], ya[2], ya[3] };
            __builtin_nontemporal_store(yo, (vfloat4*)(yp + (size_t)(tb + i) * C));
        }
    }
}

extern "C" void kernel_launch(void* const* d_in, const int* in_sizes, int n_in,
                              void* d_out, int out_size, void* d_ws, size_t ws_size,
                              hipStream_t stream)
{
    const float* td = (const float*)d_in[3];
    const float* tf = (const float*)d_in[4];
    const float* k  = (const float*)d_in[5];
    const float* v  = (const float*)d_in[6];
    float*       y  = (float*)d_out;

    const int C   = in_sizes[3];
    const int BTC = in_sizes[5];
    const int B   = BTC / (T_FIX * C);

    const int grid = B * (C / CTILE);
    wkv_fused<<<grid, NTHR, 0, stream>>>(td, tf, k, v, y, B, C);
}